// Round 6
// baseline (1016.516 us; speedup 1.0000x reference)
//
#include <hip/hip_runtime.h>

#define CONT_F 13
#define CATE_F 26
#define FF 39
#define DD 40
#define NCOMB 741
#define BB 2048
#define SUB0 40
#define SUB1 5
#define HH 100
#define K0 1560            // FF*DD rows of XT (e-part)
#define KTOT 5265          // K0 + NCOMB*SUB1 rows of XT
#define NPART 15
#define KCH 351            // 15*351 = 5265 exactly
#define CPX 93             // combs per XCD

// XT layout: [KTOT][BB] floats — k-major, batch contiguous.

// Launder a pointer into VGPRs so the compiler cannot prove wave-uniformity
// and scalarize loads to s_load (SGPR-capped) — forces global_load broadcast.
__device__ __forceinline__ const float* vgpr_ptr(const float* p) {
    unsigned long long a = (unsigned long long)p;
    asm volatile("" : "+v"(a));
    return (const float*)a;
}

// ---------------------------------------------------------------- build e -> XT rows [0,1560)
__global__ __launch_bounds__(256) void build_eT_kernel(
    const float* __restrict__ conts, const int* __restrict__ cates,
    const float* __restrict__ emb, float* __restrict__ XT)
{
    const int f = blockIdx.x;
    const int b = blockIdx.y * 256 + threadIdx.x;
    float* xo = XT + (size_t)(f * DD) * BB + b;
    if (f < CONT_F) {
        const float cv = conts[b * CONT_F + f];
        const float* em = emb + f * DD;          // f uniform -> s_load row
        #pragma unroll
        for (int d = 0; d < DD; ++d)
            xo[(size_t)d * BB] = em[d] * cv;
    } else {
        const int tok = cates[b * CATE_F + (f - CONT_F)];
        const float4* er = (const float4*)(emb + (size_t)tok * DD);
        #pragma unroll
        for (int d4 = 0; d4 < DD / 4; ++d4) {
            const float4 v = er[d4];
            xo[(size_t)(d4 * 4 + 0) * BB] = v.x;
            xo[(size_t)(d4 * 4 + 1) * BB] = v.y;
            xo[(size_t)(d4 * 4 + 2) * BB] = v.z;
            xo[(size_t)(d4 * 4 + 3) * BB] = v.w;
        }
    }
}

// ---------------------------------------------------------------- subnet
// Weights via same-address float4 GLOBAL broadcast loads (laundered pointer):
// no SGPR cap (R2/R4 stall), no LDS pipe saturation (R5 regression).
__global__ __launch_bounds__(128, 3) void subnetT_kernel(
    const float* __restrict__ XT, const float* __restrict__ w0,
    const float* __restrict__ b0, const float* __restrict__ sln0w,
    const float* __restrict__ sln0b, const float* __restrict__ w1,
    const float* __restrict__ b1, const float* __restrict__ sln1w,
    const float* __restrict__ sln1b, float* __restrict__ XTz)
{
    const int wgid   = blockIdx.x;
    const int xcd    = wgid & 7;
    const int within = wgid >> 3;           // 0..743: tl slow, comb fast
    const int c_loc  = within % CPX;
    const int tl     = within / CPX;        // 0..7 (256-row tiles)
    const int c      = xcd * CPX + c_loc;
    if (c >= NCOMB) return;
    const int col = tl * 256 + threadIdx.x * 2;

    // unrank c -> (r,s)
    int r = 0, rem = c;
    while (rem >= FF - 1 - r) { rem -= FF - 1 - r; ++r; }
    const int s = r + 1 + rem;

    const float* Pr = XT + (size_t)(r * DD) * BB + col;
    const float* Qr = XT + (size_t)(s * DD) * BB + col;
    const float* wc = vgpr_ptr(w0 + (size_t)c * (3 * DD * SUB0));
    const float* bc = b0 + c * SUB0;

    float acc0[SUB0], acc1[SUB0];
    #pragma unroll
    for (int o = 0; o < SUB0; ++o) { acc0[o] = bc[o]; acc1[o] = bc[o]; }

    #pragma unroll 2
    for (int d = 0; d < DD; ++d) {
        const float2 pv = *(const float2*)(Pr + (size_t)d * BB);
        const float2 qv = *(const float2*)(Qr + (size_t)d * BB);
        const float pq0 = pv.x * qv.x, pq1 = pv.y * qv.y;
        const float4* wp4 = (const float4*)(wc + d * SUB0);          // broadcast
        const float4* wq4 = (const float4*)(wc + 1600 + d * SUB0);
        const float4* wx4 = (const float4*)(wc + 3200 + d * SUB0);
        #pragma unroll
        for (int o4 = 0; o4 < SUB0 / 4; ++o4) {
            const float4 wp = wp4[o4];
            const float4 wq = wq4[o4];
            const float4 wx = wx4[o4];
            #define FMA1(comp, oo) { \
                const int o = o4 * 4 + oo; \
                float a0 = acc0[o], a1 = acc1[o]; \
                a0 = fmaf(wp.comp, pv.x, a0);  a1 = fmaf(wp.comp, pv.y, a1); \
                a0 = fmaf(wq.comp, qv.x, a0);  a1 = fmaf(wq.comp, qv.y, a1); \
                a0 = fmaf(wx.comp, pq0, a0);   a1 = fmaf(wx.comp, pq1, a1); \
                acc0[o] = a0; acc1[o] = a1; }
            FMA1(x, 0) FMA1(y, 1) FMA1(z, 2) FMA1(w, 3)
            #undef FMA1
        }
    }

    // LayerNorm(40) + relu per row, in-place
    #define LN40(acc) { \
        float m = 0.f; \
        _Pragma("unroll") for (int o = 0; o < SUB0; ++o) m += acc[o]; \
        m *= (1.f / SUB0); \
        float v = 0.f; \
        _Pragma("unroll") for (int o = 0; o < SUB0; ++o) { const float dl = acc[o] - m; v += dl * dl; } \
        v *= (1.f / SUB0); \
        const float inv = rsqrtf(v + 1e-5f); \
        _Pragma("unroll") for (int o = 0; o < SUB0; ++o) { \
            const float t = (acc[o] - m) * inv * sln0w[o] + sln0b[o]; \
            acc[o] = t > 0.f ? t : 0.f; } }
    LN40(acc0)
    LN40(acc1)
    #undef LN40

    // 40 -> 5
    const float* w1c = w1 + c * (SUB0 * SUB1);
    float a20[SUB1], a21[SUB1];
    #pragma unroll
    for (int j = 0; j < SUB1; ++j) { a20[j] = b1[c * SUB1 + j]; a21[j] = a20[j]; }
    #pragma unroll
    for (int k = 0; k < SUB0; ++k) {
        #pragma unroll
        for (int j = 0; j < SUB1; ++j) {
            const float wv = w1c[k * SUB1 + j];
            a20[j] = fmaf(wv, acc0[k], a20[j]);
            a21[j] = fmaf(wv, acc1[k], a21[j]);
        }
    }

    // LayerNorm(5) + relu -> XT rows K0 + c*5 + j, coalesced float2 stores
    #define LN5(a2) { \
        float m2 = 0.f; \
        _Pragma("unroll") for (int j = 0; j < SUB1; ++j) m2 += a2[j]; \
        m2 *= (1.f / SUB1); \
        float v2 = 0.f; \
        _Pragma("unroll") for (int j = 0; j < SUB1; ++j) { const float dl = a2[j] - m2; v2 += dl * dl; } \
        v2 *= (1.f / SUB1); \
        const float inv2 = rsqrtf(v2 + 1e-5f); \
        _Pragma("unroll") for (int j = 0; j < SUB1; ++j) \
            a2[j] = fmaxf((a2[j] - m2) * inv2 * sln1w[j] + sln1b[j], 0.f); }
    LN5(a20)
    LN5(a21)
    #undef LN5

    float* zo = XTz + (size_t)(K0 + c * SUB1) * BB + col;
    #pragma unroll
    for (int j = 0; j < SUB1; ++j) {
        float2 st; st.x = a20[j]; st.y = a21[j];
        *(float2*)(zo + (size_t)j * BB) = st;
    }
}

// ---------------------------------------------------------------- fc0 partials
// thread = (h-half hg, batch lane of 128); weights via same-address float4
// broadcast global loads (no LDS, no barriers). hg=0: h 0..47 (f4) + 48,49
// (f2); hg=1: h 52..99 (f4) + 50,51 (f2) — keeps all float4 bases 16B-aligned.
__global__ __launch_bounds__(256, 3) void fc0_partialT_kernel(
    const float* __restrict__ XT, const float* __restrict__ w,
    float* __restrict__ partial)
{
    const int bt = blockIdx.x;               // 0..15 (128 rows each)
    const int kc = blockIdx.y;               // 0..14
    const int l  = threadIdx.x & 127;
    const int hg = threadIdx.x >> 7;         // 0/1
    const int b  = bt * 128 + l;
    const int hb = hg ? 52 : 0;              // float4-block base (16B-aligned)
    const int h2 = hg ? 50 : 48;             // float2 pair

    const float* wrow = vgpr_ptr(w + (size_t)(kc * KCH) * HH);
    const float* xp   = XT + (size_t)(kc * KCH) * BB + b;

    float acc[48], accp0 = 0.f, accp1 = 0.f;
    #pragma unroll
    for (int j = 0; j < 48; ++j) acc[j] = 0.f;

    #pragma unroll 2
    for (int k = 0; k < KCH; ++k) {
        const float xv = xp[(size_t)k * BB];               // coalesced
        const float4* w4 = (const float4*)(wrow + (size_t)k * HH + hb);
        #pragma unroll
        for (int j4 = 0; j4 < 12; ++j4) {
            const float4 wv = w4[j4];                      // broadcast
            acc[j4 * 4 + 0] = fmaf(wv.x, xv, acc[j4 * 4 + 0]);
            acc[j4 * 4 + 1] = fmaf(wv.y, xv, acc[j4 * 4 + 1]);
            acc[j4 * 4 + 2] = fmaf(wv.z, xv, acc[j4 * 4 + 2]);
            acc[j4 * 4 + 3] = fmaf(wv.w, xv, acc[j4 * 4 + 3]);
        }
        const float2 w2 = *(const float2*)(wrow + (size_t)k * HH + h2);
        accp0 = fmaf(w2.x, xv, accp0);
        accp1 = fmaf(w2.y, xv, accp1);
    }

    float* po = partial + ((size_t)kc * BB + b) * HH;
    #pragma unroll
    for (int j4 = 0; j4 < 12; ++j4) {
        float4 st; st.x = acc[j4 * 4]; st.y = acc[j4 * 4 + 1];
        st.z = acc[j4 * 4 + 2]; st.w = acc[j4 * 4 + 3];
        *(float4*)(po + hb + j4 * 4) = st;                 // 16B-aligned
    }
    float2 st2; st2.x = accp0; st2.y = accp1;
    *(float2*)(po + h2) = st2;
}

// ---------------------------------------------------------------- fused fc0-reduce + LN + relu + fc1 + LN + out + sigmoid
__global__ __launch_bounds__(256) void fc0rh_kernel(
    const float* __restrict__ partial, const float* __restrict__ fc0b,
    const float* __restrict__ ln0w, const float* __restrict__ ln0b,
    const float* __restrict__ fc1w, const float* __restrict__ fc1b,
    const float* __restrict__ ln1w, const float* __restrict__ ln1b,
    const float* __restrict__ outw, const float* __restrict__ outb,
    float* __restrict__ out)
{
    __shared__ float xs[4][104];
    const int wl   = threadIdx.x >> 6;
    const int lane = threadIdx.x & 63;
    const int row  = blockIdx.x * 4 + wl;

    float s0 = fc0b[lane];
    float s1 = (lane < 36) ? fc0b[64 + lane] : 0.f;
    #pragma unroll
    for (int p = 0; p < NPART; ++p) {
        const float* pr = partial + ((size_t)p * BB + row) * HH;
        s0 += pr[lane];
        if (lane < 36) s1 += pr[64 + lane];
    }
    float sum = s0 + ((lane < 36) ? s1 : 0.f);
    #pragma unroll
    for (int off = 32; off; off >>= 1) sum += __shfl_xor(sum, off, 64);
    float m  = sum * 0.01f;
    float d0 = s0 - m;
    float d1 = (lane < 36) ? (s1 - m) : 0.f;
    float vs = d0 * d0 + d1 * d1;
    #pragma unroll
    for (int off = 32; off; off >>= 1) vs += __shfl_xor(vs, off, 64);
    float inv = rsqrtf(vs * 0.01f + 1e-5f);
    {
        float x0 = d0 * inv * ln0w[lane] + ln0b[lane];
        xs[wl][lane] = x0 > 0.f ? x0 : 0.f;
        if (lane < 36) {
            float x1 = d1 * inv * ln0w[64 + lane] + ln0b[64 + lane];
            xs[wl][64 + lane] = x1 > 0.f ? x1 : 0.f;
        }
    }

    float a0 = fc1b[lane];
    float a1 = (lane < 36) ? fc1b[64 + lane] : 0.f;
    for (int k = 0; k < HH; ++k) {
        const float xv = xs[wl][k];
        a0 = fmaf(fc1w[k * HH + lane], xv, a0);
        if (lane < 36) a1 = fmaf(fc1w[k * HH + 64 + lane], xv, a1);
    }
    sum = a0 + ((lane < 36) ? a1 : 0.f);
    #pragma unroll
    for (int off = 32; off; off >>= 1) sum += __shfl_xor(sum, off, 64);
    m  = sum * 0.01f;
    d0 = a0 - m;
    d1 = (lane < 36) ? (a1 - m) : 0.f;
    vs = d0 * d0 + d1 * d1;
    #pragma unroll
    for (int off = 32; off; off >>= 1) vs += __shfl_xor(vs, off, 64);
    inv = rsqrtf(vs * 0.01f + 1e-5f);

    float x0 = d0 * inv * ln1w[lane] + ln1b[lane];
    x0 = x0 > 0.f ? x0 : 0.f;
    float t = x0 * outw[lane];
    if (lane < 36) {
        float x1 = d1 * inv * ln1w[64 + lane] + ln1b[64 + lane];
        x1 = x1 > 0.f ? x1 : 0.f;
        t = fmaf(x1, outw[64 + lane], t);
    }
    #pragma unroll
    for (int off = 32; off; off >>= 1) t += __shfl_xor(t, off, 64);
    if (lane == 0) {
        const float z = t + outb[0];
        out[row] = 1.f / (1.f + expf(-z));
    }
}

// ---------------------------------------------------------------- launch
extern "C" void kernel_launch(void* const* d_in, const int* in_sizes, int n_in,
                              void* d_out, int out_size, void* d_ws, size_t ws_size,
                              hipStream_t stream)
{
    const float* conts = (const float*)d_in[0];
    const int*   cates = (const int*)d_in[1];
    const float* emb   = (const float*)d_in[3];
    const float* w0    = (const float*)d_in[4];
    const float* b0    = (const float*)d_in[5];
    const float* sln0w = (const float*)d_in[6];
    const float* sln0b = (const float*)d_in[7];
    const float* w1    = (const float*)d_in[8];
    const float* b1    = (const float*)d_in[9];
    const float* sln1w = (const float*)d_in[10];
    const float* sln1b = (const float*)d_in[11];
    const float* fc0w  = (const float*)d_in[12];
    const float* fc0b  = (const float*)d_in[13];
    const float* ln0w  = (const float*)d_in[14];
    const float* ln0b  = (const float*)d_in[15];
    const float* fc1w  = (const float*)d_in[16];
    const float* fc1b  = (const float*)d_in[17];
    const float* ln1w  = (const float*)d_in[18];
    const float* ln1b  = (const float*)d_in[19];
    const float* outw  = (const float*)d_in[20];
    const float* outb  = (const float*)d_in[21];
    float* out = (float*)d_out;

    // ws: XT (5265x2048 f32 = 43.1MB) | partial (15x2048x100 = 12.3MB) => 55.4MB
    float* XT      = (float*)d_ws;
    float* partial = XT + (size_t)KTOT * BB;

    build_eT_kernel<<<dim3(FF, BB / 256), 256, 0, stream>>>(conts, cates, emb, XT);
    subnetT_kernel<<<8 * CPX * 8, 128, 0, stream>>>(
        XT, w0, b0, sln0w, sln0b, w1, b1, sln1w, sln1b, XT);
    fc0_partialT_kernel<<<dim3(BB / 128, NPART), 256, 0, stream>>>(XT, fc0w, partial);
    fc0rh_kernel<<<BB / 4, 256, 0, stream>>>(
        partial, fc0b, ln0w, ln0b, fc1w, fc1b, ln1w, ln1b, outw, outb, out);
}

// Round 8
// 758.553 us; speedup vs baseline: 1.3401x; 1.3401x over previous
//
#include <hip/hip_runtime.h>

#define CONT_F 13
#define CATE_F 26
#define FF 39
#define DD 40
#define NCOMB 741
#define BB 2048
#define SUB0 40
#define SUB1 5
#define HH 100
#define K0 1560            // FF*DD rows of XT (e-part)
#define KTOT 5265          // K0 + NCOMB*SUB1 rows of XT
#define NPART 15
#define KCH 351            // 15*351 = 5265 exactly

using short8 = __attribute__((ext_vector_type(8))) short;   // 8 bf16 (4 VGPRs)
using f32x4  = __attribute__((ext_vector_type(4))) float;   // MFMA acc

// f32 -> bf16 RNE (finite values only)
__device__ __forceinline__ short f2bf(float f) {
    unsigned u = __float_as_uint(f);
    unsigned r = (u + 0x7FFFu + ((u >> 16) & 1u)) >> 16;
    return (short)r;
}
__device__ __forceinline__ float bf2f(short h) {
    return __uint_as_float(((unsigned)(unsigned short)h) << 16);
}

// ---------------------------------------------------------------- build e -> XT rows [0,1560)
__global__ __launch_bounds__(256) void build_eT_kernel(
    const float* __restrict__ conts, const int* __restrict__ cates,
    const float* __restrict__ emb, float* __restrict__ XT)
{
    const int f = blockIdx.x;
    const int b = blockIdx.y * 256 + threadIdx.x;
    float* xo = XT + (size_t)(f * DD) * BB + b;
    if (f < CONT_F) {
        const float cv = conts[b * CONT_F + f];
        const float* em = emb + f * DD;
        #pragma unroll
        for (int d = 0; d < DD; ++d)
            xo[(size_t)d * BB] = em[d] * cv;
    } else {
        const int tok = cates[b * CATE_F + (f - CONT_F)];
        const float4* er = (const float4*)(emb + (size_t)tok * DD);
        #pragma unroll
        for (int d4 = 0; d4 < DD / 4; ++d4) {
            const float4 v = er[d4];
            xo[(size_t)(d4 * 4 + 0) * BB] = v.x;
            xo[(size_t)(d4 * 4 + 1) * BB] = v.y;
            xo[(size_t)(d4 * 4 + 2) * BB] = v.z;
            xo[(size_t)(d4 * 4 + 3) * BB] = v.w;
        }
    }
}

// ---------------------------------------------------------------- subnet via split-bf16 MFMA
// Per block: one comb c, one batch-half (16 iters x 64 rows). C^T = W^T @ Z^T,
// A = W^T (48x128 padded, hi/lo frags in 96 VGPRs, loaded once), B = Z^T frags
// loaded DIRECTLY from k-major XT (lane l&15 = batch col -> coalesced 4-line
// loads), converted to hi/lo bf16 in-regs. 3 MFMA terms: AhBh + AhBl + AlBh.
__global__ __launch_bounds__(256, 2) void subnet_mfma_kernel(
    const float* __restrict__ XT, const float* __restrict__ w0,
    const float* __restrict__ b0, const float* __restrict__ sln0w,
    const float* __restrict__ sln0b, const float* __restrict__ w1,
    const float* __restrict__ b1, const float* __restrict__ sln1w,
    const float* __restrict__ sln1b, float* __restrict__ XTz)
{
    const int c    = blockIdx.x >> 1;
    const int half = blockIdx.x & 1;
    const int t    = threadIdx.x;
    const int w    = t >> 6;            // wave 0..3
    const int l    = t & 63;
    const int l15  = l & 15;
    const int grp  = l >> 4;            // 0..3

    // unrank c -> (r,s)
    int r = 0, rem = c;
    while (rem >= FF - 1 - r) { rem -= FF - 1 - r; ++r; }
    const int s = r + 1 + rem;
    const float* XTr = XT + (size_t)(r * DD) * BB;
    const float* XTs = XT + (size_t)(s * DD) * BB;

    // ---- prologue: A-frags (W^T hi/lo) ----
    // A[o = mt*16 + l15][k = ks*32 + grp*8 + j]; o>=40 or k>=120 -> 0
    short8 Ah[3][4], Al[3][4];
    #pragma unroll
    for (int mt = 0; mt < 3; ++mt) {
        const int o = mt * 16 + l15;
        #pragma unroll
        for (int ks = 0; ks < 4; ++ks) {
            short8 hh, ll;
            #pragma unroll
            for (int j = 0; j < 8; ++j) {
                const int k = ks * 32 + grp * 8 + j;
                const float v = (o < SUB0 && k < 120)
                    ? w0[(size_t)c * 4800 + k * SUB0 + o] : 0.f;
                const short h = f2bf(v);
                hh[j] = h;
                ll[j] = f2bf(v - bf2f(h));
            }
            Ah[mt][ks] = hh;
            Al[mt][ks] = ll;
        }
    }

    // ---- prologue: per-lane epilogue constants (C row o = mt*16 + grp*4 + rg)
    float b0r[3][4], slwr[3][4], slbr[3][4], w1r[3][4][5];
    #pragma unroll
    for (int mt = 0; mt < 3; ++mt) {
        #pragma unroll
        for (int rg = 0; rg < 4; ++rg) {
            const int o = mt * 16 + grp * 4 + rg;
            const bool re = (o < SUB0);
            b0r[mt][rg]  = re ? b0[c * SUB0 + o]   : 0.f;
            slwr[mt][rg] = re ? sln0w[o]           : 0.f;
            slbr[mt][rg] = re ? sln0b[o]           : 0.f;
            #pragma unroll
            for (int j = 0; j < 5; ++j)
                w1r[mt][rg][j] = re ? w1[(size_t)c * 200 + o * 5 + j] : 0.f;
        }
    }
    float b1r[5], s1w[5], s1b[5];
    #pragma unroll
    for (int j = 0; j < 5; ++j) {
        b1r[j] = b1[c * SUB1 + j];   // c uniform -> s_load
        s1w[j] = sln1w[j];
        s1b[j] = sln1b[j];
    }

    // ---- main loop: 16 iters x 64 batch rows ----
    for (int it = half * 16; it < half * 16 + 16; ++it) {
        const int bb = it * 64 + w * 16 + l15;     // this lane's batch col

        f32x4 acc0 = {0.f, 0.f, 0.f, 0.f};
        f32x4 acc1 = {0.f, 0.f, 0.f, 0.f};
        f32x4 acc2 = {0.f, 0.f, 0.f, 0.f};

        #pragma unroll
        for (int ks = 0; ks < 4; ++ks) {
            short8 Bh, Bl;
            #pragma unroll
            for (int j = 0; j < 8; ++j) {
                const int k = ks * 32 + grp * 8 + j;
                float v;
                if (ks == 0) {                      // k in [0,32): pure P
                    v = XTr[(size_t)k * BB + bb];
                } else {
                    const int kp = (k < 40) ? k : ((k >= 80) ? k - 80 : 0);
                    const int kq = (k >= 40) ? ((k < 80) ? k - 40 : k - 80) : 0;
                    const float vp = XTr[(size_t)kp * BB + bb];
                    const float vq = XTs[(size_t)kq * BB + bb];
                    v = (k < 40) ? vp : ((k < 80) ? vq : vp * vq);
                    if (k >= 120) v = 0.f;          // K pad
                }
                const short h = f2bf(v);
                Bh[j] = h;
                Bl[j] = f2bf(v - bf2f(h));
            }
            acc0 = __builtin_amdgcn_mfma_f32_16x16x32_bf16(Ah[0][ks], Bh, acc0, 0, 0, 0);
            acc1 = __builtin_amdgcn_mfma_f32_16x16x32_bf16(Ah[1][ks], Bh, acc1, 0, 0, 0);
            acc2 = __builtin_amdgcn_mfma_f32_16x16x32_bf16(Ah[2][ks], Bh, acc2, 0, 0, 0);
            acc0 = __builtin_amdgcn_mfma_f32_16x16x32_bf16(Ah[0][ks], Bl, acc0, 0, 0, 0);
            acc1 = __builtin_amdgcn_mfma_f32_16x16x32_bf16(Ah[1][ks], Bl, acc1, 0, 0, 0);
            acc2 = __builtin_amdgcn_mfma_f32_16x16x32_bf16(Ah[2][ks], Bl, acc2, 0, 0, 0);
            acc0 = __builtin_amdgcn_mfma_f32_16x16x32_bf16(Al[0][ks], Bh, acc0, 0, 0, 0);
            acc1 = __builtin_amdgcn_mfma_f32_16x16x32_bf16(Al[1][ks], Bh, acc1, 0, 0, 0);
            acc2 = __builtin_amdgcn_mfma_f32_16x16x32_bf16(Al[2][ks], Bh, acc2, 0, 0, 0);
        }

        // ---- epilogue: bias + LN40 + relu + (40->5) + LN5 + relu + store ----
        float vv[3][4];
        #pragma unroll
        for (int rg = 0; rg < 4; ++rg) {
            vv[0][rg] = acc0[rg] + b0r[0][rg];
            vv[1][rg] = acc1[rg] + b0r[1][rg];
            vv[2][rg] = acc2[rg] + b0r[2][rg];
        }
        float sum = 0.f, sq = 0.f;                  // pads are exact 0
        #pragma unroll
        for (int mt = 0; mt < 3; ++mt)
            #pragma unroll
            for (int rg = 0; rg < 4; ++rg) {
                const float x = vv[mt][rg];
                sum += x;
                sq = fmaf(x, x, sq);
            }
        sum += __shfl_xor(sum, 16); sum += __shfl_xor(sum, 32);
        sq  += __shfl_xor(sq, 16);  sq  += __shfl_xor(sq, 32);
        const float mean = sum * 0.025f;            // /40
        const float var  = sq * 0.025f - mean * mean;
        const float inv  = rsqrtf(var + 1e-5f);

        float p[5] = {0.f, 0.f, 0.f, 0.f, 0.f};
        #pragma unroll
        for (int mt = 0; mt < 3; ++mt)
            #pragma unroll
            for (int rg = 0; rg < 4; ++rg) {
                const float hx = fmaxf(
                    fmaf((vv[mt][rg] - mean) * inv, slwr[mt][rg], slbr[mt][rg]), 0.f);
                #pragma unroll
                for (int j = 0; j < 5; ++j)
                    p[j] = fmaf(w1r[mt][rg][j], hx, p[j]);
            }
        #pragma unroll
        for (int j = 0; j < 5; ++j) {
            p[j] += __shfl_xor(p[j], 16);
            p[j] += __shfl_xor(p[j], 32);
        }
        float a2[5];
        float sum2 = 0.f, sq2 = 0.f;
        #pragma unroll
        for (int j = 0; j < 5; ++j) {
            a2[j] = p[j] + b1r[j];
            sum2 += a2[j];
            sq2 = fmaf(a2[j], a2[j], sq2);
        }
        const float m2   = sum2 * 0.2f;
        const float var2 = sq2 * 0.2f - m2 * m2;
        const float inv2 = rsqrtf(var2 + 1e-5f);

        if (grp == 0) {                             // one copy per batch col
            float* zo = XTz + (size_t)(K0 + c * SUB1) * BB + bb;
            #pragma unroll
            for (int j = 0; j < 5; ++j) {
                const float z = fmaf((a2[j] - m2) * inv2, s1w[j], s1b[j]);
                zo[(size_t)j * BB] = z > 0.f ? z : 0.f;
            }
        }
    }
}

// ---------------------------------------------------------------- fc0 partials (R4 version)
__global__ __launch_bounds__(256) void fc0_partialT_kernel(
    const float* __restrict__ XT, const float* __restrict__ w,
    float* __restrict__ partial)
{
    __shared__ float st[64][105];
    const int rt   = blockIdx.x;
    const int kc   = blockIdx.y;
    const int rloc = threadIdx.x & 63;
    const int ob   = __builtin_amdgcn_readfirstlane((threadIdx.x >> 6) * 25);
    const int row  = rt * 64 + rloc;

    const float* xr = XT + (size_t)(kc * KCH) * BB + row;
    const float* wr = w + (size_t)(kc * KCH) * HH + ob;

    float acc[25];
    #pragma unroll
    for (int j = 0; j < 25; ++j) acc[j] = 0.f;

    #pragma unroll 3
    for (int i = 0; i < KCH; ++i) {
        const float xv = xr[(size_t)i * BB];
        const float* wk = wr + (size_t)i * HH;
        #pragma unroll
        for (int j = 0; j < 25; ++j) acc[j] = fmaf(wk[j], xv, acc[j]);
    }
    #pragma unroll
    for (int j = 0; j < 25; ++j) st[rloc][ob + j] = acc[j];
    __syncthreads();

    float* po = partial + ((size_t)kc * BB + rt * 64) * HH;
    #pragma unroll
    for (int k = 0; k < 25; ++k) {
        const int idx = k * 256 + threadIdx.x;
        const int rr = idx / 100, hh = idx % 100;
        po[idx] = st[rr][hh];
    }
}

// ---------------------------------------------------------------- fused fc0-reduce + LN + relu + fc1 + LN + out + sigmoid
__global__ __launch_bounds__(256) void fc0rh_kernel(
    const float* __restrict__ partial, const float* __restrict__ fc0b,
    const float* __restrict__ ln0w, const float* __restrict__ ln0b,
    const float* __restrict__ fc1w, const float* __restrict__ fc1b,
    const float* __restrict__ ln1w, const float* __restrict__ ln1b,
    const float* __restrict__ outw, const float* __restrict__ outb,
    float* __restrict__ out)
{
    __shared__ float xs[4][104];
    const int wl   = threadIdx.x >> 6;
    const int lane = threadIdx.x & 63;
    const int row  = blockIdx.x * 4 + wl;

    float s0 = fc0b[lane];
    float s1 = (lane < 36) ? fc0b[64 + lane] : 0.f;
    #pragma unroll
    for (int p = 0; p < NPART; ++p) {
        const float* pr = partial + ((size_t)p * BB + row) * HH;
        s0 += pr[lane];
        if (lane < 36) s1 += pr[64 + lane];
    }
    float sum = s0 + ((lane < 36) ? s1 : 0.f);
    #pragma unroll
    for (int off = 32; off; off >>= 1) sum += __shfl_xor(sum, off, 64);
    float m  = sum * 0.01f;
    float d0 = s0 - m;
    float d1 = (lane < 36) ? (s1 - m) : 0.f;
    float vs = d0 * d0 + d1 * d1;
    #pragma unroll
    for (int off = 32; off; off >>= 1) vs += __shfl_xor(vs, off, 64);
    float inv = rsqrtf(vs * 0.01f + 1e-5f);
    {
        float x0 = d0 * inv * ln0w[lane] + ln0b[lane];
        xs[wl][lane] = x0 > 0.f ? x0 : 0.f;
        if (lane < 36) {
            float x1 = d1 * inv * ln0w[64 + lane] + ln0b[64 + lane];
            xs[wl][64 + lane] = x1 > 0.f ? x1 : 0.f;
        }
    }

    float a0 = fc1b[lane];
    float a1 = (lane < 36) ? fc1b[64 + lane] : 0.f;
    for (int k = 0; k < HH; ++k) {
        const float xv = xs[wl][k];
        a0 = fmaf(fc1w[k * HH + lane], xv, a0);
        if (lane < 36) a1 = fmaf(fc1w[k * HH + 64 + lane], xv, a1);
    }
    sum = a0 + ((lane < 36) ? a1 : 0.f);
    #pragma unroll
    for (int off = 32; off; off >>= 1) sum += __shfl_xor(sum, off, 64);
    m  = sum * 0.01f;
    d0 = a0 - m;
    d1 = (lane < 36) ? (a1 - m) : 0.f;
    vs = d0 * d0 + d1 * d1;
    #pragma unroll
    for (int off = 32; off; off >>= 1) vs += __shfl_xor(vs, off, 64);
    inv = rsqrtf(vs * 0.01f + 1e-5f);

    float x0 = d0 * inv * ln1w[lane] + ln1b[lane];
    x0 = x0 > 0.f ? x0 : 0.f;
    float t = x0 * outw[lane];
    if (lane < 36) {
        float x1 = d1 * inv * ln1w[64 + lane] + ln1b[64 + lane];
        x1 = x1 > 0.f ? x1 : 0.f;
        t = fmaf(x1, outw[64 + lane], t);
    }
    #pragma unroll
    for (int off = 32; off; off >>= 1) t += __shfl_xor(t, off, 64);
    if (lane == 0) {
        const float z = t + outb[0];
        out[row] = 1.f / (1.f + expf(-z));
    }
}

// ---------------------------------------------------------------- launch
extern "C" void kernel_launch(void* const* d_in, const int* in_sizes, int n_in,
                              void* d_out, int out_size, void* d_ws, size_t ws_size,
                              hipStream_t stream)
{
    const float* conts = (const float*)d_in[0];
    const int*   cates = (const int*)d_in[1];
    const float* emb   = (const float*)d_in[3];
    const float* w0    = (const float*)d_in[4];
    const float* b0    = (const float*)d_in[5];
    const float* sln0w = (const float*)d_in[6];
    const float* sln0b = (const float*)d_in[7];
    const float* w1    = (const float*)d_in[8];
    const float* b1    = (const float*)d_in[9];
    const float* sln1w = (const float*)d_in[10];
    const float* sln1b = (const float*)d_in[11];
    const float* fc0w  = (const float*)d_in[12];
    const float* fc0b  = (const float*)d_in[13];
    const float* ln0w  = (const float*)d_in[14];
    const float* ln0b  = (const float*)d_in[15];
    const float* fc1w  = (const float*)d_in[16];
    const float* fc1b  = (const float*)d_in[17];
    const float* ln1w  = (const float*)d_in[18];
    const float* ln1b  = (const float*)d_in[19];
    const float* outw  = (const float*)d_in[20];
    const float* outb  = (const float*)d_in[21];
    float* out = (float*)d_out;

    // ws: XT (5265x2048 f32 = 43.1MB) | partial (15x2048x100 = 12.3MB)
    float* XT      = (float*)d_ws;
    float* partial = XT + (size_t)KTOT * BB;

    build_eT_kernel<<<dim3(FF, BB / 256), 256, 0, stream>>>(conts, cates, emb, XT);
    subnet_mfma_kernel<<<NCOMB * 2, 256, 0, stream>>>(
        XT, w0, b0, sln0w, sln0b, w1, b1, sln1w, sln1b, XT);
    fc0_partialT_kernel<<<dim3(BB / 64, NPART), 256, 0, stream>>>(XT, fc0w, partial);
    fc0rh_kernel<<<BB / 4, 256, 0, stream>>>(
        partial, fc0b, ln0w, ln0b, fc1w, fc1b, ln1w, ln1b, outw, outb, out);
}